// Round 1
// baseline (1621.162 us; speedup 1.0000x reference)
//
#include <hip/hip_runtime.h>

// Problem constants (fixed by setup_inputs)
#define HQ 32
#define HKV 32
#define DH 128
#define HID 4096
#define BATCH 4
#define SEQ 1024
#define TOK (BATCH * SEQ)          // 4096
#define NQKV 12288                 // (HQ + 2*HKV) * DH
#define CACHE_ROWS 8192            // NUM_BLOCKS * BLOCK_SIZE
#define SM_SCALE 0.08838834764831845f  // 1/sqrt(128)

typedef unsigned short u16;
typedef __bf16 bf16x8 __attribute__((ext_vector_type(8)));
typedef float floatx4 __attribute__((ext_vector_type(4)));

__device__ __forceinline__ u16 f2bf(float x) {
  unsigned u = __float_as_uint(x);
  u += 0x7FFF + ((u >> 16) & 1);   // RNE
  return (u16)(u >> 16);
}
__device__ __forceinline__ float bf2f(u16 h) {
  return __uint_as_float(((unsigned)h) << 16);
}
// async global->LDS, 16B per lane. LDS dest is wave-uniform base + lane*16:
// callers must pass per-lane pointers that are lane-contiguous within a wave.
__device__ __forceinline__ void cp16(const void* g, void* l) {
  __builtin_amdgcn_global_load_lds(
      (__attribute__((address_space(1))) unsigned int*)(g),
      (__attribute__((address_space(3))) unsigned int*)(l), 16, 0, 0);
}

// ---------------- fp32 -> bf16 elementwise ----------------
__global__ void k_f32_to_bf16(const float4* __restrict__ x, ushort4* __restrict__ y) {
  int i = blockIdx.x * 256 + threadIdx.x;
  float4 v = x[i];
  ushort4 o;
  o.x = f2bf(v.x); o.y = f2bf(v.y); o.z = f2bf(v.z); o.w = f2bf(v.w);
  y[i] = o;
}

// ---------------- fp32 KxN -> bf16 NxK transpose ----------------
__global__ void k_transpose_bf16(const float* __restrict__ W, u16* __restrict__ Wt,
                                 int Kd, int Nd) {
  __shared__ float t[64][65];
  int n0 = blockIdx.x << 6, k0 = blockIdx.y << 6;
  int tx = threadIdx.x & 63, ty = threadIdx.x >> 6;
#pragma unroll
  for (int r = ty; r < 64; r += 4)
    t[r][tx] = W[(size_t)(k0 + r) * Nd + n0 + tx];
  __syncthreads();
#pragma unroll
  for (int r = ty; r < 64; r += 4)
    Wt[(size_t)(n0 + r) * Kd + k0 + tx] = f2bf(t[tx][r]);
}

// ---------------- bf16 GEMM: C[M,N] = A[M,K] * Bt[N,K]^T ----------------
// 128x128 tile, BK=32, 256 thr (4 waves, 2x2 of 64x64), mfma_f32_16x16x32_bf16.
template <int Nd, int Kd, bool OUT_BF16>
__global__ __launch_bounds__(256, 2) void k_gemm(const u16* __restrict__ A,
                                                 const u16* __restrict__ Bt,
                                                 void* __restrict__ Cp) {
  __shared__ __align__(16) u16 lA[128 * 32];  // [m][k]
  __shared__ __align__(16) u16 lB[128 * 32];  // [n][k]
  const int tid = threadIdx.x;
  const int bm = blockIdx.y << 7, bn = blockIdx.x << 7;
  const int wave = tid >> 6, lane = tid & 63;
  const int wr = (wave >> 1) << 6, wc = (wave & 1) << 6;
  const int quad = lane >> 4, l16 = lane & 15;

  // staging: 512 chunks of 16B per tile; thread handles chunk tid and tid+256
  const int row0 = tid >> 2, colc = (tid & 3) << 3;
  const u16* gA0 = A + (size_t)(bm + row0) * Kd + colc;
  const u16* gA1 = gA0 + (size_t)64 * Kd;
  const u16* gB0 = Bt + (size_t)(bn + row0) * Kd + colc;
  const u16* gB1 = gB0 + (size_t)64 * Kd;
  u16* lA0 = &lA[tid * 8];
  u16* lA1 = &lA[(tid + 256) * 8];
  u16* lB0 = &lB[tid * 8];
  u16* lB1 = &lB[(tid + 256) * 8];

  const int abase = (wr + l16) * 32 + quad * 8;
  const int bbase = (wc + l16) * 32 + quad * 8;

  const floatx4 FZ4 = {0.f, 0.f, 0.f, 0.f};
  floatx4 acc[4][4];
#pragma unroll
  for (int i = 0; i < 4; ++i)
#pragma unroll
    for (int j = 0; j < 4; ++j) acc[i][j] = FZ4;

  for (int k0 = 0; k0 < Kd; k0 += 32) {
    __syncthreads();
    cp16(gA0 + k0, lA0);
    cp16(gA1 + k0, lA1);
    cp16(gB0 + k0, lB0);
    cp16(gB1 + k0, lB1);
    __syncthreads();
    bf16x8 af[4], bfr[4];
#pragma unroll
    for (int mi = 0; mi < 4; ++mi)
      af[mi] = *(const bf16x8*)&lA[abase + mi * 512];
#pragma unroll
    for (int ni = 0; ni < 4; ++ni)
      bfr[ni] = *(const bf16x8*)&lB[bbase + ni * 512];
#pragma unroll
    for (int mi = 0; mi < 4; ++mi)
#pragma unroll
      for (int ni = 0; ni < 4; ++ni)
        acc[mi][ni] = __builtin_amdgcn_mfma_f32_16x16x32_bf16(af[mi], bfr[ni],
                                                              acc[mi][ni], 0, 0, 0);
  }
  // epilogue: C row = quad*4+reg, col = lane&15 (verified m89/m91 layout)
  const int rbase = bm + wr + quad * 4;
  const int cbase = bn + wc + l16;
#pragma unroll
  for (int mi = 0; mi < 4; ++mi)
#pragma unroll
    for (int ni = 0; ni < 4; ++ni)
#pragma unroll
      for (int r = 0; r < 4; ++r) {
        size_t idx = (size_t)(rbase + mi * 16 + r) * Nd + (cbase + ni * 16);
        if (OUT_BF16)
          ((u16*)Cp)[idx] = f2bf(acc[mi][ni][r]);
        else
          ((float*)Cp)[idx] = acc[mi][ni][r];
      }
}

// ---------------- RoPE + layout + cache scatter ----------------
// qkv (bf16, [T][12288]) -> qb (bf16, b,h,s,d; scaled), kb (bf16, b,h,s,d),
// kc/vc (fp32 cache rows at slots[t])
__global__ void k_rope_scatter(const u16* __restrict__ qkv, const float* __restrict__ cosp,
                               const float* __restrict__ sinp, const int* __restrict__ slots,
                               u16* __restrict__ qb, u16* __restrict__ kb,
                               float* __restrict__ kc, float* __restrict__ vc) {
  const int t = blockIdx.x;
  const int b = t >> 10, s = t & 1023;
  const int tid = threadIdx.x;
  __shared__ float lc[64], ls[64];
  if (tid < 64) lc[tid] = cosp[t * 64 + tid];
  else if (tid < 128) ls[tid - 64] = sinp[t * 64 + (tid - 64)];
  __syncthreads();
  const int slot = slots[t];
  const u16* base = qkv + (size_t)t * NQKV;
#pragma unroll
  for (int it = 0; it < 8; ++it) {  // Q: 32 heads x 64 pairs
    int w = it * 256 + tid;
    int h = w >> 6, i = w & 63;
    float x1 = bf2f(base[h * 128 + i]);
    float x2 = bf2f(base[h * 128 + 64 + i]);
    float c = lc[i], sn = ls[i];
    size_t o = ((size_t)(b * HQ + h) * SEQ + s) * DH + i;
    qb[o] = f2bf((x1 * c - x2 * sn) * SM_SCALE);
    qb[o + 64] = f2bf((x2 * c + x1 * sn) * SM_SCALE);
  }
#pragma unroll
  for (int it = 0; it < 8; ++it) {  // K
    int w = it * 256 + tid;
    int h = w >> 6, i = w & 63;
    float x1 = bf2f(base[HQ * DH + h * 128 + i]);
    float x2 = bf2f(base[HQ * DH + h * 128 + 64 + i]);
    float c = lc[i], sn = ls[i];
    float y1 = x1 * c - x2 * sn;
    float y2 = x2 * c + x1 * sn;
    size_t o = ((size_t)(b * HKV + h) * SEQ + s) * DH + i;
    kb[o] = f2bf(y1);
    kb[o + 64] = f2bf(y2);
    size_t oc = (size_t)slot * (HKV * DH) + h * 128 + i;
    kc[oc] = y1;
    kc[oc + 64] = y2;
  }
#pragma unroll
  for (int it = 0; it < 16; ++it) {  // V -> cache (no rope)
    int w = it * 256 + tid;
    vc[(size_t)slot * (HKV * DH) + w] = bf2f(base[2 * HQ * DH + w]);
  }
}

// ---------------- V transpose: qkv v-slice -> vT (b,h,d,s) bf16 ----------------
__global__ void k_vt(const u16* __restrict__ qkv, u16* __restrict__ vT) {
  __shared__ u16 t[64][66];
  const int bh = blockIdx.z;
  const int b = bh >> 5, h = bh & 31;
  const int s0 = blockIdx.y << 6, d0 = blockIdx.x << 6;
  const int tx = threadIdx.x & 63, ty = threadIdx.x >> 6;
#pragma unroll
  for (int r = ty; r < 64; r += 4)
    t[r][tx] = qkv[(size_t)(b * SEQ + s0 + r) * NQKV + 2 * HQ * DH + h * DH + d0 + tx];
  __syncthreads();
#pragma unroll
  for (int r = ty; r < 64; r += 4)
    vT[((size_t)bh * DH + d0 + r) * SEQ + s0 + tx] = t[tx][r];
}

// ---------------- flash attention (causal) ----------------
// block = (qtile 64 rows, head, batch); 4 waves, wave w owns q rows [w*16, w*16+16)
__global__ __launch_bounds__(256, 2) void k_attn(const u16* __restrict__ qb,
                                                 const u16* __restrict__ kb,
                                                 const u16* __restrict__ vT,
                                                 u16* __restrict__ attn) {
  __shared__ __align__(16) u16 lK[64 * 128];  // [ki][d]
  __shared__ __align__(16) u16 lV[128 * 64];  // [d][ki]
  __shared__ __align__(16) u16 lP[64 * 64];   // [q][ki]
  const int qt = blockIdx.x, h = blockIdx.y, b = blockIdx.z;
  const int bh = b * HQ + h;
  const int q0 = qt << 6;
  const int tid = threadIdx.x, wave = tid >> 6, lane = tid & 63;
  const int quad = lane >> 4, l16 = lane & 15;
  const u16* Qb = qb + (size_t)bh * SEQ * DH;
  const u16* Kb = kb + (size_t)bh * SEQ * DH;
  const u16* Vb = vT + (size_t)bh * DH * SEQ;

  bf16x8 qf[4];  // A-operand frags: m=lane&15, k=quad*8+j  (held for whole block)
#pragma unroll
  for (int ds = 0; ds < 4; ++ds)
    qf[ds] = *(const bf16x8*)&Qb[(size_t)(q0 + wave * 16 + l16) * DH + ds * 32 + quad * 8];

  const floatx4 FZ4 = {0.f, 0.f, 0.f, 0.f};
  floatx4 acc_o[8];
#pragma unroll
  for (int i = 0; i < 8; ++i) acc_o[i] = FZ4;
  float m_i[4] = {-1e30f, -1e30f, -1e30f, -1e30f};
  float l_i[4] = {0.f, 0.f, 0.f, 0.f};

  for (int kt = 0; kt <= qt; ++kt) {
    const int k0 = kt << 6;
    __syncthreads();  // previous iter's LDS reads done before restaging
    const u16* Ks = Kb + (size_t)k0 * DH;  // K tile is contiguous 16KB
#pragma unroll
    for (int p = 0; p < 4; ++p) {
      int c = tid + p * 256;
      cp16(Ks + c * 8, &lK[c * 8]);
    }
#pragma unroll
    for (int p = 0; p < 4; ++p) {
      int c = tid + p * 256;
      cp16(Vb + (size_t)(c >> 3) * SEQ + k0 + (c & 7) * 8, &lV[c * 8]);
    }
    __syncthreads();

    // S = Q K^T (scale folded into Q)
    floatx4 accs[4];
#pragma unroll
    for (int ni = 0; ni < 4; ++ni) {
      accs[ni] = FZ4;
#pragma unroll
      for (int ds = 0; ds < 4; ++ds) {
        bf16x8 kf = *(const bf16x8*)&lK[(ni * 16 + l16) * 128 + ds * 32 + quad * 8];
        accs[ni] = __builtin_amdgcn_mfma_f32_16x16x32_bf16(qf[ds], kf, accs[ni], 0, 0, 0);
      }
    }
    if (kt == qt) {  // diagonal tile: causal mask
#pragma unroll
      for (int ni = 0; ni < 4; ++ni) {
        int ki = k0 + ni * 16 + l16;
#pragma unroll
        for (int r = 0; r < 4; ++r) {
          int qr = q0 + wave * 16 + quad * 4 + r;
          if (ki > qr) accs[ni][r] = -1e30f;
        }
      }
    }
    // online softmax; rows live on 16 lanes of a quad -> shfl_xor 1,2,4,8
    float mnew[4], alpha[4];
#pragma unroll
    for (int r = 0; r < 4; ++r) {
      float mx = fmaxf(fmaxf(accs[0][r], accs[1][r]), fmaxf(accs[2][r], accs[3][r]));
#pragma unroll
      for (int off = 1; off < 16; off <<= 1) mx = fmaxf(mx, __shfl_xor(mx, off));
      mnew[r] = fmaxf(m_i[r], mx);
      alpha[r] = __expf(m_i[r] - mnew[r]);
      m_i[r] = mnew[r];
    }
    float rs[4] = {0.f, 0.f, 0.f, 0.f};
#pragma unroll
    for (int ni = 0; ni < 4; ++ni)
#pragma unroll
      for (int r = 0; r < 4; ++r) {
        float p = __expf(accs[ni][r] - mnew[r]);
        rs[r] += p;
        lP[(wave * 16 + quad * 4 + r) * 64 + ni * 16 + l16] = f2bf(p);
      }
#pragma unroll
    for (int r = 0; r < 4; ++r) {
      float sr = rs[r];
#pragma unroll
      for (int off = 1; off < 16; off <<= 1) sr += __shfl_xor(sr, off);
      l_i[r] = l_i[r] * alpha[r] + sr;
    }
#pragma unroll
    for (int dt = 0; dt < 8; ++dt)
#pragma unroll
      for (int r = 0; r < 4; ++r) acc_o[dt][r] *= alpha[r];

    // O += P V  (P read back in A-operand layout; wave-local rows, no barrier)
    bf16x8 pf[2];
#pragma unroll
    for (int ks = 0; ks < 2; ++ks)
      pf[ks] = *(const bf16x8*)&lP[(wave * 16 + l16) * 64 + ks * 32 + quad * 8];
#pragma unroll
    for (int dt = 0; dt < 8; ++dt)
#pragma unroll
      for (int ks = 0; ks < 2; ++ks) {
        bf16x8 vf = *(const bf16x8*)&lV[(dt * 16 + l16) * 64 + ks * 32 + quad * 8];
        acc_o[dt] = __builtin_amdgcn_mfma_f32_16x16x32_bf16(pf[ks], vf, acc_o[dt], 0, 0, 0);
      }
  }
  float inv[4];
#pragma unroll
  for (int r = 0; r < 4; ++r) inv[r] = 1.0f / l_i[r];
#pragma unroll
  for (int dt = 0; dt < 8; ++dt)
#pragma unroll
    for (int r = 0; r < 4; ++r) {
      int tok = b * SEQ + q0 + wave * 16 + quad * 4 + r;
      attn[(size_t)tok * HID + h * DH + dt * 16 + l16] = f2bf(acc_o[dt][r] * inv[r]);
    }
}

// ---------------- launcher ----------------
extern "C" void kernel_launch(void* const* d_in, const int* in_sizes, int n_in,
                              void* d_out, int out_size, void* d_ws, size_t ws_size,
                              hipStream_t stream) {
  (void)in_sizes; (void)n_in; (void)out_size; (void)ws_size;
  const float* hs = (const float*)d_in[0];
  const float* cosp = (const float*)d_in[1];
  const float* sinp = (const float*)d_in[2];
  const float* qkv_w = (const float*)d_in[3];
  const float* o_w = (const float*)d_in[4];
  const int* slots = (const int*)d_in[8];

  float* out = (float*)d_out;                          // (T, HID) fp32
  float* kc = out + (size_t)TOK * HID;                 // (8192, 32, 128) fp32
  float* vc = kc + (size_t)CACHE_ROWS * HKV * DH;

  // workspace layout (224 MiB), stream-ordered aliasing:
  //  regA (96MB): W1t  -> then qb | kb | vT
  //  regB (96MB): qkv  -> then W2t (after v-transpose consumed qkv)
  //  regC (32MB): hs_bf16 -> then attn
  u16* regA = (u16*)d_ws;
  u16* regB = regA + (size_t)NQKV * HID;
  u16* regC = regB + (size_t)TOK * NQKV;
  u16* W1t = regA;
  u16* qb = regA;
  u16* kb = qb + (size_t)BATCH * HQ * SEQ * DH;
  u16* vTp = kb + (size_t)BATCH * HKV * SEQ * DH;
  u16* qkv = regB;
  u16* W2t = regB;
  u16* hsb = regC;
  u16* attnb = regC;

  // cache outputs: zero everything once (re-poisoned每call), scatter overwrites rows
  hipMemsetAsync(kc, 0, (size_t)2 * CACHE_ROWS * HKV * DH * sizeof(float), stream);

  k_f32_to_bf16<<<TOK * HID / 1024, 256, 0, stream>>>((const float4*)hs, (ushort4*)hsb);
  k_transpose_bf16<<<dim3(NQKV / 64, HID / 64), 256, 0, stream>>>(qkv_w, W1t, HID, NQKV);
  k_gemm<NQKV, HID, true><<<dim3(NQKV / 128, TOK / 128), 256, 0, stream>>>(hsb, W1t, qkv);
  k_rope_scatter<<<TOK, 256, 0, stream>>>(qkv, cosp, sinp, slots, qb, kb, kc, vc);
  k_vt<<<dim3(DH / 64, SEQ / 64, BATCH * HKV), 256, 0, stream>>>(qkv, vTp);
  k_transpose_bf16<<<dim3(HID / 64, HID / 64), 256, 0, stream>>>(o_w, W2t, HID, HID);
  k_attn<<<dim3(SEQ / 64, HQ, BATCH), 256, 0, stream>>>(qb, kb, vTp, attnb);
  k_gemm<HID, HID, false><<<dim3(HID / 128, TOK / 128), 256, 0, stream>>>(attnb, W2t, out);
}